// Round 8
// baseline (70.862 us; speedup 1.0000x reference)
//
#include <hip/hip_runtime.h>
#include <hip/hip_bf16.h>

// Problem constants (from reference)
#define Hd   768
#define Bsz  4
#define Ent  42
#define Mm   16
#define NEGV (-1e9f)

#define GM 2688          // B*E*M rows
#define GN 1536          // concat(head, tail) outputs
#define GK 768
#define NT (GK / 32)     // 24 K-steps

typedef short bf16x8 __attribute__((ext_vector_type(8)));
typedef float f32x4  __attribute__((ext_vector_type(4)));
typedef unsigned short u16x8 __attribute__((ext_vector_type(8)));
typedef unsigned short u16x4 __attribute__((ext_vector_type(4)));

static __device__ __forceinline__ unsigned short f2bf(float x) {
    unsigned int u = __float_as_uint(x);
    u += 0x7fffu + ((u >> 16) & 1u);          // RNE
    return (unsigned short)(u >> 16);
}
static __device__ __forceinline__ float bf2f(unsigned short v) {
    return __uint_as_float(((unsigned int)v) << 16);
}

// ---------------------------------------------------------------------------
// Kernel 0: fp32 -> bf16 conversion + zero-init of ch/qt/cqt accumulators.
// ---------------------------------------------------------------------------
__global__ __launch_bounds__(256)
void to_bf16(const float* __restrict__ me, const float* __restrict__ wh,
             const float* __restrict__ wt, unsigned short* __restrict__ dst,
             float* __restrict__ dots)   // ch||qt||cqt, 3*GM floats
{
    const int t = blockIdx.x * 256 + threadIdx.x;
    if (t < 3 * GM / 4) {                              // 2016 float4 = 8064 f
        float4 z = {0.f, 0.f, 0.f, 0.f};
        reinterpret_cast<float4*>(dots)[t] = z;
    }
    const size_t e = (size_t)t * 8;
    const size_t row = e / Hd;                         // 8 | 768 so no straddle
    const float* src;
    size_t off;
    if (row < 2688)      { src = me; off = e; }
    else if (row < 3456) { src = wh; off = e - (size_t)2688 * Hd; }
    else                 { src = wt; off = e - (size_t)3456 * Hd; }
    float4 v0 = *reinterpret_cast<const float4*>(src + off);
    float4 v1 = *reinterpret_cast<const float4*>(src + off + 4);
    u16x8 o;
    o[0] = f2bf(v0.x); o[1] = f2bf(v0.y); o[2] = f2bf(v0.z); o[3] = f2bf(v0.w);
    o[4] = f2bf(v1.x); o[5] = f2bf(v1.y); o[6] = f2bf(v1.z); o[7] = f2bf(v1.w);
    *reinterpret_cast<u16x8*>(dst + e) = o;
}

// ---------------------------------------------------------------------------
// Kernel 1: DIRECT-VMEM bf16 MFMA GEMM + ReLU + fused row-dots.
// Key fact: for this row-major NT GEMM, every 16x16x32 fragment is 16
// CONTIGUOUS bytes of global memory (8 consecutive bf16 along K of one row),
// so fragments load straight into VGPRs -- no LDS, no barriers, no staging.
// A frags are 4x wave-redundant (served by L1); B frags L2-resident.
// Epilogue: relu -> bf16 store, plus partial dot of each row with
// w_c (head) / w_q,w_cq (tail) over this block's 128 cols, shfl-reduced
// across the 16 frow lanes and atomicAdd'ed into ch/qt/cqt.
// ---------------------------------------------------------------------------
__global__ __launch_bounds__(256)
void gemm_direct(const unsigned short* __restrict__ Ab,
                 const unsigned short* __restrict__ Wb,
                 unsigned short* __restrict__ f_head,
                 unsigned short* __restrict__ f_tail,
                 const float* __restrict__ w_c, const float* __restrict__ w_q,
                 const float* __restrict__ w_cq,
                 float* __restrict__ ch, float* __restrict__ qt,
                 float* __restrict__ cqt)
{
    const int tid  = threadIdx.x;
    const int wave = tid >> 6;
    const int lane = tid & 63;
    const int n0 = blockIdx.x * 128;
    const int m0 = blockIdx.y * 64;
    const int frow = lane & 15;      // A row / B row (C col) within frag
    const int kg   = lane >> 4;      // k-group 0..3
    const int koff = kg * 8;         // k elements

    // 6 fragment base pointers; all 24 K-steps reachable via imm offsets
    const unsigned short* ar0 = Ab + (size_t)(m0 +  0 + frow) * GK + koff;
    const unsigned short* ar1 = Ab + (size_t)(m0 + 16 + frow) * GK + koff;
    const unsigned short* ar2 = Ab + (size_t)(m0 + 32 + frow) * GK + koff;
    const unsigned short* ar3 = Ab + (size_t)(m0 + 48 + frow) * GK + koff;
    const int nb = n0 + wave * 32 + frow;
    const unsigned short* br0 = Wb + (size_t)nb * GK + koff;
    const unsigned short* br1 = Wb + (size_t)(nb + 16) * GK + koff;

    f32x4 acc[4][2];
    {
        f32x4 z = {0.f, 0.f, 0.f, 0.f};
        #pragma unroll
        for (int mi = 0; mi < 4; ++mi) { acc[mi][0] = z; acc[mi][1] = z; }
    }

    #pragma unroll
    for (int t = 0; t < NT; ++t) {
        const int kb = t * 32;       // elements
        bf16x8 a0 = *reinterpret_cast<const bf16x8*>(ar0 + kb);
        bf16x8 a1 = *reinterpret_cast<const bf16x8*>(ar1 + kb);
        bf16x8 a2 = *reinterpret_cast<const bf16x8*>(ar2 + kb);
        bf16x8 a3 = *reinterpret_cast<const bf16x8*>(ar3 + kb);
        bf16x8 b0 = *reinterpret_cast<const bf16x8*>(br0 + kb);
        bf16x8 b1 = *reinterpret_cast<const bf16x8*>(br1 + kb);
        acc[0][0] = __builtin_amdgcn_mfma_f32_16x16x32_bf16(a0, b0, acc[0][0], 0, 0, 0);
        acc[0][1] = __builtin_amdgcn_mfma_f32_16x16x32_bf16(a0, b1, acc[0][1], 0, 0, 0);
        acc[1][0] = __builtin_amdgcn_mfma_f32_16x16x32_bf16(a1, b0, acc[1][0], 0, 0, 0);
        acc[1][1] = __builtin_amdgcn_mfma_f32_16x16x32_bf16(a1, b1, acc[1][1], 0, 0, 0);
        acc[2][0] = __builtin_amdgcn_mfma_f32_16x16x32_bf16(a2, b0, acc[2][0], 0, 0, 0);
        acc[2][1] = __builtin_amdgcn_mfma_f32_16x16x32_bf16(a2, b1, acc[2][1], 0, 0, 0);
        acc[3][0] = __builtin_amdgcn_mfma_f32_16x16x32_bf16(a3, b0, acc[3][0], 0, 0, 0);
        acc[3][1] = __builtin_amdgcn_mfma_f32_16x16x32_bf16(a3, b1, acc[3][1], 0, 0, 0);
    }

    // ---- epilogue: relu, bf16 store, fused partial dots ----
    // C/D layout (m89-verified): col = frow, row = kg*4 + reg.
    const bool isHead = (n0 < Hd);
    unsigned short* outp = isHead ? f_head : f_tail;
    const int nloc = (isHead ? n0 : (n0 - Hd)) + wave * 32 + frow;  // local col
    const int rbase = m0 + kg * 4;

    const float* w0 = isHead ? w_c : w_q;
    const float w0a = w0[nloc], w0b = w0[nloc + 16];
    const float w1a = isHead ? 0.f : w_cq[nloc];
    const float w1b = isHead ? 0.f : w_cq[nloc + 16];

    float p0[4][4], p1[4][4];
    #pragma unroll
    for (int mi = 0; mi < 4; ++mi)
        #pragma unroll
        for (int j = 0; j < 4; ++j) {
            const float va = fmaxf(acc[mi][0][j], 0.f);
            const float vb = fmaxf(acc[mi][1][j], 0.f);
            const size_t r = (size_t)(rbase + mi * 16 + j) * Hd + nloc;
            outp[r]      = f2bf(va);
            outp[r + 16] = f2bf(vb);
            p0[mi][j] = va * w0a + vb * w0b;
            p1[mi][j] = va * w1a + vb * w1b;
        }

    // reduce over the 16 frow lanes (xor 1,2,4,8 stays within kg group)
    #pragma unroll
    for (int s = 1; s <= 8; s <<= 1)
        #pragma unroll
        for (int mi = 0; mi < 4; ++mi)
            #pragma unroll
            for (int j = 0; j < 4; ++j) {
                p0[mi][j] += __shfl_xor(p0[mi][j], s);
                if (!isHead) p1[mi][j] += __shfl_xor(p1[mi][j], s);
            }

    if (frow == 0) {
        float* d0 = isHead ? ch : qt;
        #pragma unroll
        for (int mi = 0; mi < 4; ++mi)
            #pragma unroll
            for (int j = 0; j < 4; ++j) {
                const int r = rbase + mi * 16 + j;
                atomicAdd(&d0[r], p0[mi][j]);
                if (!isHead) atomicAdd(&cqt[r], p1[mi][j]);
            }
    }
}

// ---------------------------------------------------------------------------
// Kernel 2: ONE WAVE PER PAIR attention (identical to round 7).
// ---------------------------------------------------------------------------
__global__ __launch_bounds__(256)
void pair_attn(const unsigned short* __restrict__ f_head,
               const unsigned short* __restrict__ f_tail,
               const float* __restrict__ ch, const float* __restrict__ qt,
               const float* __restrict__ cqt,
               const float* __restrict__ entity_embed,
               const int* __restrict__ mention_num,
               const int* __restrict__ b_ind, const int* __restrict__ h_ind,
               const int* __restrict__ t_ind,
               float* __restrict__ out, int N)
{
    const int tid  = threadIdx.x;
    const int wave = tid >> 6;
    const int lane = tid & 63;

    __shared__ float hwS[4][16];
    __shared__ float twS[4][16];

    int n = blockIdx.x * 4 + wave;
    if (n >= N) n = N - 1;      // duplicate pair: identical writes, deterministic

    const int b = b_ind[n], h = h_ind[n], t = t_ind[n];
    const int eh = b * Ent + h, et = b * Ent + t;
    const int rh = eh * Mm, rt = et * Mm;
    const int hn = mention_num[eh], tn = mention_num[et];

    const int i  = lane >> 2;       // score row 0..15
    const int jg = lane & 3;        // col group: cols jg*4 .. jg*4+3

    const float chi = ch[rh + i];
    const float cqi = cqt[rt + i];
    const float4 q4 = *reinterpret_cast<const float4*>(qt + rt + jg * 4);
    const u16x4 f4  = *reinterpret_cast<const u16x4*>(
                          f_head + (size_t)(rh + i) * Hd + jg * 4);
    float v[4];
    #pragma unroll
    for (int k = 0; k < 4; ++k) {
        const int j = jg * 4 + k;
        const float qv = (k == 0) ? q4.x : (k == 1) ? q4.y : (k == 2) ? q4.z : q4.w;
        v[k] = (i < hn && j < tn) ? (chi + qv + cqi * bf2f(f4[k])) : NEGV;
    }

    float rm = fmaxf(fmaxf(v[0], v[1]), fmaxf(v[2], v[3]));
    rm = fmaxf(rm, __shfl_xor(rm, 1));
    rm = fmaxf(rm, __shfl_xor(rm, 2));

    float cm[4];
    #pragma unroll
    for (int k = 0; k < 4; ++k) {
        cm[k] = v[k];
        cm[k] = fmaxf(cm[k], __shfl_xor(cm[k], 4));
        cm[k] = fmaxf(cm[k], __shfl_xor(cm[k], 8));
        cm[k] = fmaxf(cm[k], __shfl_xor(cm[k], 16));
        cm[k] = fmaxf(cm[k], __shfl_xor(cm[k], 32));
    }

    float gm = rm;
    gm = fmaxf(gm, __shfl_xor(gm, 4));
    gm = fmaxf(gm, __shfl_xor(gm, 8));
    gm = fmaxf(gm, __shfl_xor(gm, 16));
    gm = fmaxf(gm, __shfl_xor(gm, 32));
    const float eh_ = expf(rm - gm);
    float S = eh_;
    S += __shfl_xor(S, 4);
    S += __shfl_xor(S, 8);
    S += __shfl_xor(S, 16);
    S += __shfl_xor(S, 32);
    const float hwv = eh_ / S;

    float gmt = fmaxf(fmaxf(cm[0], cm[1]), fmaxf(cm[2], cm[3]));
    gmt = fmaxf(gmt, __shfl_xor(gmt, 1));
    gmt = fmaxf(gmt, __shfl_xor(gmt, 2));
    float et_[4];
    float St = 0.f;
    #pragma unroll
    for (int k = 0; k < 4; ++k) { et_[k] = expf(cm[k] - gmt); St += et_[k]; }
    St += __shfl_xor(St, 1);
    St += __shfl_xor(St, 2);

    if (jg == 0) hwS[wave][i] = hwv;
    if (lane < 4) {
        #pragma unroll
        for (int k = 0; k < 4; ++k) twS[wave][lane * 4 + k] = et_[k] / St;
    }
    __syncthreads();

    const size_t oh = (size_t)n * (2 * Hd);
    const size_t ot = (size_t)(N + n) * (2 * Hd);
    const unsigned short* fhp = f_head + (size_t)rh * Hd;
    const unsigned short* ftp = f_tail + (size_t)rt * Hd;

    #pragma unroll
    for (int c = 0; c < 3; ++c) {
        const int col = c * 256 + lane * 4;
        float a0 = 0.f, a1 = 0.f, a2 = 0.f, a3 = 0.f;
        for (int ii = 0; ii < hn; ++ii) {
            const u16x4 fv = *reinterpret_cast<const u16x4*>(fhp + (size_t)ii * Hd + col);
            const float w = hwS[wave][ii];
            a0 += w * bf2f(fv[0]); a1 += w * bf2f(fv[1]);
            a2 += w * bf2f(fv[2]); a3 += w * bf2f(fv[3]);
        }
        float4 o = {a0, a1, a2, a3};
        *reinterpret_cast<float4*>(out + oh + Hd + col) = o;
    }
    #pragma unroll
    for (int c = 0; c < 3; ++c) {
        const int col = c * 256 + lane * 4;
        float a0 = 0.f, a1 = 0.f, a2 = 0.f, a3 = 0.f;
        for (int ii = 0; ii < tn; ++ii) {
            const u16x4 fv = *reinterpret_cast<const u16x4*>(ftp + (size_t)ii * Hd + col);
            const float w = twS[wave][ii];
            a0 += w * bf2f(fv[0]); a1 += w * bf2f(fv[1]);
            a2 += w * bf2f(fv[2]); a3 += w * bf2f(fv[3]);
        }
        float4 o = {a0, a1, a2, a3};
        *reinterpret_cast<float4*>(out + ot + Hd + col) = o;
    }

    const float4* ehp = reinterpret_cast<const float4*>(entity_embed + (size_t)eh * Hd);
    const float4* etp = reinterpret_cast<const float4*>(entity_embed + (size_t)et * Hd);
    #pragma unroll
    for (int c = 0; c < 3; ++c) {
        const int g = c * 64 + lane;
        reinterpret_cast<float4*>(out + oh)[g] = ehp[g];
        reinterpret_cast<float4*>(out + ot)[g] = etp[g];
    }
}

// ---------------------------------------------------------------------------
extern "C" void kernel_launch(void* const* d_in, const int* in_sizes, int n_in,
                              void* d_out, int out_size, void* d_ws, size_t ws_size,
                              hipStream_t stream)
{
    const float* entity_embed  = (const float*)d_in[0];
    const float* mention_embed = (const float*)d_in[1];
    // d_in[2] sent_embed, d_in[3] entity_info: unused by reference
    const int*   mention_num   = (const int*)d_in[4];
    const int*   b_ind         = (const int*)d_in[5];
    const int*   h_ind         = (const int*)d_in[6];
    const int*   t_ind         = (const int*)d_in[7];
    const float* W_head        = (const float*)d_in[8];
    const float* W_tail        = (const float*)d_in[9];
    const float* w_c           = (const float*)d_in[10];
    const float* w_q           = (const float*)d_in[11];
    const float* w_cq          = (const float*)d_in[12];
    float* out = (float*)d_out;

    const int N = in_sizes[5];            // 4096

    // workspace layout (bf16 activations): total ~14.8 MiB
    unsigned short* Ab     = (unsigned short*)d_ws;          // [2688*768]
    unsigned short* Wb     = Ab + (size_t)GM * GK;           // [1536*768] (head||tail)
    unsigned short* f_head = Wb + (size_t)GN * GK;           // [2688*768]
    unsigned short* f_tail = f_head + (size_t)GM * Hd;       // [2688*768]
    float* ch  = (float*)(f_tail + (size_t)GM * Hd);         // [2688]
    float* qt  = ch + GM;                                    // [2688]
    float* cqt = qt + GM;                                    // [2688]

    // 0) convert inputs to bf16 + zero the dot accumulators
    to_bf16<<<(GM + GN) * GK / (8 * 256), 256, 0, stream>>>(
        mention_embed, W_head, W_tail, Ab, ch);

    // 1) direct-VMEM GEMM + ReLU + fused row-dots
    dim3 gg(GN / 128, GM / 64);           // (12, 42) = 504 blocks
    gemm_direct<<<gg, 256, 0, stream>>>(Ab, Wb, f_head, f_tail,
                                        w_c, w_q, w_cq, ch, qt, cqt);

    // 2) per-pair attention + output (wave per pair)
    pair_attn<<<(N + 3) / 4, 256, 0, stream>>>(f_head, f_tail, ch, qt, cqt,
                                               entity_embed, mention_num,
                                               b_ind, h_ind, t_ind, out, N);
}

// Round 9
// 52.776 us; speedup vs baseline: 1.3427x; 1.3427x over previous
//
#include <hip/hip_runtime.h>
#include <hip/hip_bf16.h>

// Problem constants (from reference)
#define Hd   768
#define Bsz  4
#define Ent  42
#define Mm   16
#define NEGV (-1e9f)

#define GM 2688          // B*E*M rows
#define GN 1536          // concat(head, tail) outputs
#define GK 768
#define NT (GK / 32)     // 24 K-steps

typedef short bf16x8 __attribute__((ext_vector_type(8)));
typedef float f32x4  __attribute__((ext_vector_type(4)));
typedef unsigned short u16x8 __attribute__((ext_vector_type(8)));
typedef unsigned short u16x4 __attribute__((ext_vector_type(4)));

static __device__ __forceinline__ unsigned short f2bf(float x) {
    unsigned int u = __float_as_uint(x);
    u += 0x7fffu + ((u >> 16) & 1u);          // RNE
    return (unsigned short)(u >> 16);
}
static __device__ __forceinline__ float bf2f(unsigned short v) {
    return __uint_as_float(((unsigned int)v) << 16);
}

// ---------------------------------------------------------------------------
// Kernel 0: fp32 -> bf16 conversion + zero-init of ch/qt/cqt accumulators.
// (round-8 proven)
// ---------------------------------------------------------------------------
__global__ __launch_bounds__(256)
void to_bf16(const float* __restrict__ me, const float* __restrict__ wh,
             const float* __restrict__ wt, unsigned short* __restrict__ dst,
             float* __restrict__ dots)   // ch||qt||cqt, 3*GM floats
{
    const int t = blockIdx.x * 256 + threadIdx.x;
    if (t < 3 * GM / 4) {                              // 2016 float4 = 8064 f
        float4 z = {0.f, 0.f, 0.f, 0.f};
        reinterpret_cast<float4*>(dots)[t] = z;
    }
    const size_t e = (size_t)t * 8;
    const size_t row = e / Hd;                         // 8 | 768 so no straddle
    const float* src;
    size_t off;
    if (row < 2688)      { src = me; off = e; }
    else if (row < 3456) { src = wh; off = e - (size_t)2688 * Hd; }
    else                 { src = wt; off = e - (size_t)3456 * Hd; }
    float4 v0 = *reinterpret_cast<const float4*>(src + off);
    float4 v1 = *reinterpret_cast<const float4*>(src + off + 4);
    u16x8 o;
    o[0] = f2bf(v0.x); o[1] = f2bf(v0.y); o[2] = f2bf(v0.z); o[3] = f2bf(v0.w);
    o[4] = f2bf(v1.x); o[5] = f2bf(v1.y); o[6] = f2bf(v1.z); o[7] = f2bf(v1.w);
    *reinterpret_cast<u16x8*>(dst + e) = o;
}

// ---------------------------------------------------------------------------
// Kernel 1: LDS-staged bf16 MFMA GEMM + ReLU (round-5/7 proven K-loop)
//           + fused row-dots epilogue (round-8 proven).
// 64x128 tile (MxN), BK=32, 4 waves, dbuf 2-phase prefetch via
// global_load_lds width=16.  Epilogue: relu -> bf16 store + partial dot of
// each output row with w_c (head) / w_q,w_cq (tail) over this block's 128
// cols, shfl-reduced across the 16 frow lanes, atomicAdd'ed into ch/qt/cqt.
// ---------------------------------------------------------------------------
__global__ __launch_bounds__(256)
void gemm_mfma(const unsigned short* __restrict__ Ab,
               const unsigned short* __restrict__ Wb,
               unsigned short* __restrict__ f_head,
               unsigned short* __restrict__ f_tail,
               const float* __restrict__ w_c, const float* __restrict__ w_q,
               const float* __restrict__ w_cq,
               float* __restrict__ ch, float* __restrict__ qt,
               float* __restrict__ cqt)
{
    __shared__ unsigned short As[2][64 * 32];    // 4 KB per buf
    __shared__ unsigned short Bs[2][128 * 32];   // 8 KB per buf

    const int tid  = threadIdx.x;
    const int wave = tid >> 6;
    const int lane = tid & 63;
    const int n0 = blockIdx.x * 128;
    const int m0 = blockIdx.y * 64;

    const int srow = wave * 16 + (lane >> 2);          // 0..63
    const int scol = (lane & 3) * 8;                   // elements
    const unsigned short* Aga = Ab + (size_t)(m0 + srow) * GK + scol;
    const unsigned short* Bga = Wb + (size_t)(n0 + srow) * GK + scol;

#define STAGE(buf, k0) do { \
    __builtin_amdgcn_global_load_lds((const __attribute__((address_space(1))) void*)(Aga + (k0)), \
        (__attribute__((address_space(3))) void*)(As[buf] + wave * 512), 16, 0, 0); \
    __builtin_amdgcn_global_load_lds((const __attribute__((address_space(1))) void*)(Bga + (k0)), \
        (__attribute__((address_space(3))) void*)(Bs[buf] + wave * 512), 16, 0, 0); \
    __builtin_amdgcn_global_load_lds((const __attribute__((address_space(1))) void*)(Bga + 64 * GK + (k0)), \
        (__attribute__((address_space(3))) void*)(Bs[buf] + 2048 + wave * 512), 16, 0, 0); \
} while (0)

    const int frow = lane & 15;
    const int kg   = lane >> 4;
    const int koff = kg * 8;

    f32x4 acc[4][2];
    {
        f32x4 z = {0.f, 0.f, 0.f, 0.f};
        #pragma unroll
        for (int mi = 0; mi < 4; ++mi) { acc[mi][0] = z; acc[mi][1] = z; }
    }

    STAGE(0, 0);
    int cur = 0;
    #pragma unroll 1
    for (int t = 0; t < NT; ++t) {
        __syncthreads();                 // drains vmcnt: buf[cur] ready
        if (t < NT - 1) STAGE(cur ^ 1, (t + 1) * 32);
        const unsigned short* ap = As[cur] + frow * 32 + koff;
        const unsigned short* bp = Bs[cur] + (wave * 32 + frow) * 32 + koff;
        bf16x8 a[4], b[2];
        #pragma unroll
        for (int mi = 0; mi < 4; ++mi)
            a[mi] = *reinterpret_cast<const bf16x8*>(ap + mi * 16 * 32);
        b[0] = *reinterpret_cast<const bf16x8*>(bp);
        b[1] = *reinterpret_cast<const bf16x8*>(bp + 16 * 32);
        #pragma unroll
        for (int mi = 0; mi < 4; ++mi) {
            acc[mi][0] = __builtin_amdgcn_mfma_f32_16x16x32_bf16(a[mi], b[0], acc[mi][0], 0, 0, 0);
            acc[mi][1] = __builtin_amdgcn_mfma_f32_16x16x32_bf16(a[mi], b[1], acc[mi][1], 0, 0, 0);
        }
        cur ^= 1;
    }
#undef STAGE

    // ---- epilogue: relu, bf16 store, fused partial dots (round-8 proven) --
    // C/D layout (m89-verified): col = frow, row = kg*4 + reg.
    const bool isHead = (n0 < Hd);
    unsigned short* outp = isHead ? f_head : f_tail;
    const int nloc = (isHead ? n0 : (n0 - Hd)) + wave * 32 + frow;  // local col
    const int rbase = m0 + kg * 4;

    const float* w0 = isHead ? w_c : w_q;
    const float w0a = w0[nloc], w0b = w0[nloc + 16];
    const float w1a = isHead ? 0.f : w_cq[nloc];
    const float w1b = isHead ? 0.f : w_cq[nloc + 16];

    float p0[4][4], p1[4][4];
    #pragma unroll
    for (int mi = 0; mi < 4; ++mi)
        #pragma unroll
        for (int j = 0; j < 4; ++j) {
            const float va = fmaxf(acc[mi][0][j], 0.f);
            const float vb = fmaxf(acc[mi][1][j], 0.f);
            const size_t r = (size_t)(rbase + mi * 16 + j) * Hd + nloc;
            outp[r]      = f2bf(va);
            outp[r + 16] = f2bf(vb);
            p0[mi][j] = va * w0a + vb * w0b;
            p1[mi][j] = va * w1a + vb * w1b;
        }

    // reduce over the 16 frow lanes (xor 1,2,4,8 stays within kg group)
    #pragma unroll
    for (int s = 1; s <= 8; s <<= 1)
        #pragma unroll
        for (int mi = 0; mi < 4; ++mi)
            #pragma unroll
            for (int j = 0; j < 4; ++j) {
                p0[mi][j] += __shfl_xor(p0[mi][j], s);
                if (!isHead) p1[mi][j] += __shfl_xor(p1[mi][j], s);
            }

    if (frow == 0) {
        float* d0 = isHead ? ch : qt;
        #pragma unroll
        for (int mi = 0; mi < 4; ++mi)
            #pragma unroll
            for (int j = 0; j < 4; ++j) {
                const int r = rbase + mi * 16 + j;
                atomicAdd(&d0[r], p0[mi][j]);
                if (!isHead) atomicAdd(&cqt[r], p1[mi][j]);
            }
    }
}

// ---------------------------------------------------------------------------
// Kernel 2: ONE WAVE PER PAIR attention (byte-identical to round 7).
// ---------------------------------------------------------------------------
__global__ __launch_bounds__(256)
void pair_attn(const unsigned short* __restrict__ f_head,
               const unsigned short* __restrict__ f_tail,
               const float* __restrict__ ch, const float* __restrict__ qt,
               const float* __restrict__ cqt,
               const float* __restrict__ entity_embed,
               const int* __restrict__ mention_num,
               const int* __restrict__ b_ind, const int* __restrict__ h_ind,
               const int* __restrict__ t_ind,
               float* __restrict__ out, int N)
{
    const int tid  = threadIdx.x;
    const int wave = tid >> 6;
    const int lane = tid & 63;

    __shared__ float hwS[4][16];
    __shared__ float twS[4][16];

    int n = blockIdx.x * 4 + wave;
    if (n >= N) n = N - 1;      // duplicate pair: identical writes, deterministic

    const int b = b_ind[n], h = h_ind[n], t = t_ind[n];
    const int eh = b * Ent + h, et = b * Ent + t;
    const int rh = eh * Mm, rt = et * Mm;
    const int hn = mention_num[eh], tn = mention_num[et];

    const int i  = lane >> 2;       // score row 0..15
    const int jg = lane & 3;        // col group: cols jg*4 .. jg*4+3

    const float chi = ch[rh + i];
    const float cqi = cqt[rt + i];
    const float4 q4 = *reinterpret_cast<const float4*>(qt + rt + jg * 4);
    const u16x4 f4  = *reinterpret_cast<const u16x4*>(
                          f_head + (size_t)(rh + i) * Hd + jg * 4);
    float v[4];
    #pragma unroll
    for (int k = 0; k < 4; ++k) {
        const int j = jg * 4 + k;
        const float qv = (k == 0) ? q4.x : (k == 1) ? q4.y : (k == 2) ? q4.z : q4.w;
        v[k] = (i < hn && j < tn) ? (chi + qv + cqi * bf2f(f4[k])) : NEGV;
    }

    float rm = fmaxf(fmaxf(v[0], v[1]), fmaxf(v[2], v[3]));
    rm = fmaxf(rm, __shfl_xor(rm, 1));
    rm = fmaxf(rm, __shfl_xor(rm, 2));

    float cm[4];
    #pragma unroll
    for (int k = 0; k < 4; ++k) {
        cm[k] = v[k];
        cm[k] = fmaxf(cm[k], __shfl_xor(cm[k], 4));
        cm[k] = fmaxf(cm[k], __shfl_xor(cm[k], 8));
        cm[k] = fmaxf(cm[k], __shfl_xor(cm[k], 16));
        cm[k] = fmaxf(cm[k], __shfl_xor(cm[k], 32));
    }

    float gm = rm;
    gm = fmaxf(gm, __shfl_xor(gm, 4));
    gm = fmaxf(gm, __shfl_xor(gm, 8));
    gm = fmaxf(gm, __shfl_xor(gm, 16));
    gm = fmaxf(gm, __shfl_xor(gm, 32));
    const float eh_ = expf(rm - gm);
    float S = eh_;
    S += __shfl_xor(S, 4);
    S += __shfl_xor(S, 8);
    S += __shfl_xor(S, 16);
    S += __shfl_xor(S, 32);
    const float hwv = eh_ / S;

    float gmt = fmaxf(fmaxf(cm[0], cm[1]), fmaxf(cm[2], cm[3]));
    gmt = fmaxf(gmt, __shfl_xor(gmt, 1));
    gmt = fmaxf(gmt, __shfl_xor(gmt, 2));
    float et_[4];
    float St = 0.f;
    #pragma unroll
    for (int k = 0; k < 4; ++k) { et_[k] = expf(cm[k] - gmt); St += et_[k]; }
    St += __shfl_xor(St, 1);
    St += __shfl_xor(St, 2);

    if (jg == 0) hwS[wave][i] = hwv;
    if (lane < 4) {
        #pragma unroll
        for (int k = 0; k < 4; ++k) twS[wave][lane * 4 + k] = et_[k] / St;
    }
    __syncthreads();

    const size_t oh = (size_t)n * (2 * Hd);
    const size_t ot = (size_t)(N + n) * (2 * Hd);
    const unsigned short* fhp = f_head + (size_t)rh * Hd;
    const unsigned short* ftp = f_tail + (size_t)rt * Hd;

    #pragma unroll
    for (int c = 0; c < 3; ++c) {
        const int col = c * 256 + lane * 4;
        float a0 = 0.f, a1 = 0.f, a2 = 0.f, a3 = 0.f;
        for (int ii = 0; ii < hn; ++ii) {
            const u16x4 fv = *reinterpret_cast<const u16x4*>(fhp + (size_t)ii * Hd + col);
            const float w = hwS[wave][ii];
            a0 += w * bf2f(fv[0]); a1 += w * bf2f(fv[1]);
            a2 += w * bf2f(fv[2]); a3 += w * bf2f(fv[3]);
        }
        float4 o = {a0, a1, a2, a3};
        *reinterpret_cast<float4*>(out + oh + Hd + col) = o;
    }
    #pragma unroll
    for (int c = 0; c < 3; ++c) {
        const int col = c * 256 + lane * 4;
        float a0 = 0.f, a1 = 0.f, a2 = 0.f, a3 = 0.f;
        for (int ii = 0; ii < tn; ++ii) {
            const u16x4 fv = *reinterpret_cast<const u16x4*>(ftp + (size_t)ii * Hd + col);
            const float w = twS[wave][ii];
            a0 += w * bf2f(fv[0]); a1 += w * bf2f(fv[1]);
            a2 += w * bf2f(fv[2]); a3 += w * bf2f(fv[3]);
        }
        float4 o = {a0, a1, a2, a3};
        *reinterpret_cast<float4*>(out + ot + Hd + col) = o;
    }

    const float4* ehp = reinterpret_cast<const float4*>(entity_embed + (size_t)eh * Hd);
    const float4* etp = reinterpret_cast<const float4*>(entity_embed + (size_t)et * Hd);
    #pragma unroll
    for (int c = 0; c < 3; ++c) {
        const int g = c * 64 + lane;
        reinterpret_cast<float4*>(out + oh)[g] = ehp[g];
        reinterpret_cast<float4*>(out + ot)[g] = etp[g];
    }
}

// ---------------------------------------------------------------------------
extern "C" void kernel_launch(void* const* d_in, const int* in_sizes, int n_in,
                              void* d_out, int out_size, void* d_ws, size_t ws_size,
                              hipStream_t stream)
{
    const float* entity_embed  = (const float*)d_in[0];
    const float* mention_embed = (const float*)d_in[1];
    // d_in[2] sent_embed, d_in[3] entity_info: unused by reference
    const int*   mention_num   = (const int*)d_in[4];
    const int*   b_ind         = (const int*)d_in[5];
    const int*   h_ind         = (const int*)d_in[6];
    const int*   t_ind         = (const int*)d_in[7];
    const float* W_head        = (const float*)d_in[8];
    const float* W_tail        = (const float*)d_in[9];
    const float* w_c           = (const float*)d_in[10];
    const float* w_q           = (const float*)d_in[11];
    const float* w_cq          = (const float*)d_in[12];
    float* out = (float*)d_out;

    const int N = in_sizes[5];            // 4096

    // workspace layout (bf16 activations): total ~14.8 MiB
    unsigned short* Ab     = (unsigned short*)d_ws;          // [2688*768]
    unsigned short* Wb     = Ab + (size_t)GM * GK;           // [1536*768] (head||tail)
    unsigned short* f_head = Wb + (size_t)GN * GK;           // [2688*768]
    unsigned short* f_tail = f_head + (size_t)GM * Hd;       // [2688*768]
    float* ch  = (float*)(f_tail + (size_t)GM * Hd);         // [2688]
    float* qt  = ch + GM;                                    // [2688]
    float* cqt = qt + GM;                                    // [2688]

    // 0) convert inputs to bf16 + zero the dot accumulators
    to_bf16<<<(GM + GN) * GK / (8 * 256), 256, 0, stream>>>(
        mention_embed, W_head, W_tail, Ab, ch);

    // 1) LDS-staged GEMM + ReLU + fused row-dots
    dim3 gg(GN / 128, GM / 64);           // (12, 42) = 504 blocks
    gemm_mfma<<<gg, 256, 0, stream>>>(Ab, Wb, f_head, f_tail,
                                      w_c, w_q, w_cq, ch, qt, cqt);

    // 2) per-pair attention + output (wave per pair)
    pair_attn<<<(N + 3) / 4, 256, 0, stream>>>(f_head, f_tail, ch, qt, cqt,
                                               entity_embed, mention_num,
                                               b_ind, h_ind, t_ind, out, N);
}

// Round 10
// 47.043 us; speedup vs baseline: 1.5063x; 1.1219x over previous
//
#include <hip/hip_runtime.h>
#include <hip/hip_bf16.h>

// Problem constants (from reference)
#define Hd   768
#define Bsz  4
#define Ent  42
#define Mm   16
#define NEGV (-1e9f)

#define GM 2688          // B*E*M rows
#define GN 1536          // concat(head, tail) outputs
#define GK 768
#define NT2 (GK / 64)    // 12 K-steps of 64

typedef short bf16x8 __attribute__((ext_vector_type(8)));
typedef float f32x4  __attribute__((ext_vector_type(4)));
typedef unsigned short u16x8 __attribute__((ext_vector_type(8)));
typedef unsigned short u16x4 __attribute__((ext_vector_type(4)));

static __device__ __forceinline__ unsigned short f2bf(float x) {
    unsigned int u = __float_as_uint(x);
    u += 0x7fffu + ((u >> 16) & 1u);          // RNE
    return (unsigned short)(u >> 16);
}
static __device__ __forceinline__ float bf2f(unsigned short v) {
    return __uint_as_float(((unsigned int)v) << 16);
}

// ---------------------------------------------------------------------------
// Kernel 0: fp32 -> bf16 conversion (round-7 proven).
// ---------------------------------------------------------------------------
__global__ __launch_bounds__(256)
void to_bf16(const float* __restrict__ me, const float* __restrict__ wh,
             const float* __restrict__ wt, unsigned short* __restrict__ dst)
{
    const int t = blockIdx.x * 256 + threadIdx.x;
    const size_t e = (size_t)t * 8;
    const size_t row = e / Hd;                         // 8 | 768 so no straddle
    const float* src;
    size_t off;
    if (row < 2688)      { src = me; off = e; }
    else if (row < 3456) { src = wh; off = e - (size_t)2688 * Hd; }
    else                 { src = wt; off = e - (size_t)3456 * Hd; }
    float4 v0 = *reinterpret_cast<const float4*>(src + off);
    float4 v1 = *reinterpret_cast<const float4*>(src + off + 4);
    u16x8 o;
    o[0] = f2bf(v0.x); o[1] = f2bf(v0.y); o[2] = f2bf(v0.z); o[3] = f2bf(v0.w);
    o[4] = f2bf(v1.x); o[5] = f2bf(v1.y); o[6] = f2bf(v1.z); o[7] = f2bf(v1.w);
    *reinterpret_cast<u16x8*>(dst + e) = o;
}

// ---------------------------------------------------------------------------
// Kernel 1: bf16 MFMA GEMM + ReLU.  64x128 tile (MxN), BK=64, 4 waves,
// dbuf 2-phase prefetch.  vs round 7: BK 32->64 halves the per-barrier
// vmcnt(0) drains (12 instead of 24) and doubles compute per drain.
// 128B LDS rows would be bank-degenerate, so the T2 XOR-swizzle is applied
// BOTH sides (rule #21): pre-swizzled per-lane global SOURCE column
// (LDS dst stays linear as global_load_lds requires) + swizzled read offset
// byte ^= ((row&7)<<4).  K accumulation order identical to round 7 ->
// bit-identical results.
// ---------------------------------------------------------------------------
__global__ __launch_bounds__(256)
void gemm_mfma(const unsigned short* __restrict__ Ab,
               const unsigned short* __restrict__ Wb,
               unsigned short* __restrict__ f_head,
               unsigned short* __restrict__ f_tail)
{
    __shared__ unsigned short As[2][64 * 64];    //  8 KB per buf
    __shared__ unsigned short Bs[2][128 * 64];   // 16 KB per buf

    const int tid  = threadIdx.x;
    const int wave = tid >> 6;
    const int lane = tid & 63;
    const int n0 = blockIdx.x * 128;
    const int m0 = blockIdx.y * 64;

    // staging: each gload_lds op moves 8 rows x 128B; lane l -> row l>>3,
    // byte col (l&7)*16, with the source column XOR-swizzled by the row.
    const int sr8   = lane >> 3;                       // 0..7 row in stripe
    const int scolE = ((lane & 7) ^ sr8) * 8;          // swizzled src col (elems)
    const unsigned short* AgaBase = Ab + (size_t)(m0 + wave * 16 + sr8) * GK + scolE;
    const unsigned short* BgaBase = Wb + (size_t)(n0 + wave * 32 + sr8) * GK + scolE;

#define STAGE(buf, k0) do { \
    __builtin_amdgcn_global_load_lds((const __attribute__((address_space(1))) void*)(AgaBase + (k0)), \
        (__attribute__((address_space(3))) void*)(As[buf] + (wave * 16) * 64), 16, 0, 0); \
    __builtin_amdgcn_global_load_lds((const __attribute__((address_space(1))) void*)(AgaBase + 8 * GK + (k0)), \
        (__attribute__((address_space(3))) void*)(As[buf] + (wave * 16 + 8) * 64), 16, 0, 0); \
    __builtin_amdgcn_global_load_lds((const __attribute__((address_space(1))) void*)(BgaBase + (k0)), \
        (__attribute__((address_space(3))) void*)(Bs[buf] + (wave * 32) * 64), 16, 0, 0); \
    __builtin_amdgcn_global_load_lds((const __attribute__((address_space(1))) void*)(BgaBase + 8 * GK + (k0)), \
        (__attribute__((address_space(3))) void*)(Bs[buf] + (wave * 32 + 8) * 64), 16, 0, 0); \
    __builtin_amdgcn_global_load_lds((const __attribute__((address_space(1))) void*)(BgaBase + 16 * GK + (k0)), \
        (__attribute__((address_space(3))) void*)(Bs[buf] + (wave * 32 + 16) * 64), 16, 0, 0); \
    __builtin_amdgcn_global_load_lds((const __attribute__((address_space(1))) void*)(BgaBase + 24 * GK + (k0)), \
        (__attribute__((address_space(3))) void*)(Bs[buf] + (wave * 32 + 24) * 64), 16, 0, 0); \
} while (0)

    const int frow = lane & 15;
    const int kg   = lane >> 4;
    const int f7x  = (frow & 7) << 4;                  // byte XOR key (row-det.)
    const int rdE0 = ((kg * 16)      ^ f7x) >> 1;      // elems, k-half 0
    const int rdE1 = ((kg * 16 + 64) ^ f7x) >> 1;      // elems, k-half 1

    f32x4 acc[4][2];
    {
        f32x4 z = {0.f, 0.f, 0.f, 0.f};
        #pragma unroll
        for (int mi = 0; mi < 4; ++mi) { acc[mi][0] = z; acc[mi][1] = z; }
    }

    STAGE(0, 0);
    int cur = 0;
    #pragma unroll 1
    for (int t = 0; t < NT2; ++t) {
        __syncthreads();                 // drains vmcnt: buf[cur] ready
        if (t < NT2 - 1) STAGE(cur ^ 1, (t + 1) * 64);
        const unsigned short* a_ = As[cur] + frow * 64;
        const unsigned short* b_ = Bs[cur] + (wave * 32 + frow) * 64;
        bf16x8 a[4][2], b[2][2];
        #pragma unroll
        for (int mi = 0; mi < 4; ++mi) {
            a[mi][0] = *reinterpret_cast<const bf16x8*>(a_ + mi * 16 * 64 + rdE0);
            a[mi][1] = *reinterpret_cast<const bf16x8*>(a_ + mi * 16 * 64 + rdE1);
        }
        #pragma unroll
        for (int ni = 0; ni < 2; ++ni) {
            b[ni][0] = *reinterpret_cast<const bf16x8*>(b_ + ni * 16 * 64 + rdE0);
            b[ni][1] = *reinterpret_cast<const bf16x8*>(b_ + ni * 16 * 64 + rdE1);
        }
        #pragma unroll
        for (int kk = 0; kk < 2; ++kk)           // ascending k: bit-identical
            #pragma unroll
            for (int mi = 0; mi < 4; ++mi) {
                acc[mi][0] = __builtin_amdgcn_mfma_f32_16x16x32_bf16(a[mi][kk], b[0][kk], acc[mi][0], 0, 0, 0);
                acc[mi][1] = __builtin_amdgcn_mfma_f32_16x16x32_bf16(a[mi][kk], b[1][kk], acc[mi][1], 0, 0, 0);
            }
        cur ^= 1;
    }
#undef STAGE

    // C/D layout (m89-verified): col = frow, row = kg*4 + reg.
    const bool isHead = (n0 < Hd);
    unsigned short* outp = isHead ? f_head : f_tail;
    const int nbase = (isHead ? n0 : (n0 - Hd)) + wave * 32 + frow;
    const int rbase = m0 + kg * 4;
    #pragma unroll
    for (int mi = 0; mi < 4; ++mi)
        #pragma unroll
        for (int ni = 0; ni < 2; ++ni)
            #pragma unroll
            for (int j = 0; j < 4; ++j) {
                float v = fmaxf(acc[mi][ni][j], 0.f);
                outp[(size_t)(rbase + mi * 16 + j) * Hd + nbase + ni * 16] = f2bf(v);
            }
}

// ---------------------------------------------------------------------------
// Kernel 2: per-row dots (round-7 proven).
// ---------------------------------------------------------------------------
__global__ __launch_bounds__(256)
void row_dots(const unsigned short* __restrict__ f_head,
              const unsigned short* __restrict__ f_tail,
              const float* __restrict__ w_c, const float* __restrict__ w_q,
              const float* __restrict__ w_cq,
              float* __restrict__ ch, float* __restrict__ qt, float* __restrict__ cqt)
{
    const int wave = threadIdx.x >> 6;
    const int lane = threadIdx.x & 63;
    const int r = blockIdx.x * 4 + wave;
    const unsigned short* fh = f_head + (size_t)r * Hd;
    const unsigned short* ft = f_tail + (size_t)r * Hd;
    float pc = 0.f, pq = 0.f, pcq = 0.f;
    #pragma unroll
    for (int j = 0; j < Hd / 64; ++j) {
        const int c = j * 64 + lane;
        float vh = bf2f(fh[c]), vt = bf2f(ft[c]);
        pc += vh * w_c[c]; pq += vt * w_q[c]; pcq += vt * w_cq[c];
    }
    #pragma unroll
    for (int s = 32; s >= 1; s >>= 1) {
        pc  += __shfl_down(pc, s);
        pq  += __shfl_down(pq, s);
        pcq += __shfl_down(pcq, s);
    }
    if (lane == 0) { ch[r] = pc; qt[r] = pq; cqt[r] = pcq; }
}

// ---------------------------------------------------------------------------
// Kernel 3: ONE WAVE PER PAIR attention (byte-identical to round 7).
// ---------------------------------------------------------------------------
__global__ __launch_bounds__(256)
void pair_attn(const unsigned short* __restrict__ f_head,
               const unsigned short* __restrict__ f_tail,
               const float* __restrict__ ch, const float* __restrict__ qt,
               const float* __restrict__ cqt,
               const float* __restrict__ entity_embed,
               const int* __restrict__ mention_num,
               const int* __restrict__ b_ind, const int* __restrict__ h_ind,
               const int* __restrict__ t_ind,
               float* __restrict__ out, int N)
{
    const int tid  = threadIdx.x;
    const int wave = tid >> 6;
    const int lane = tid & 63;

    __shared__ float hwS[4][16];
    __shared__ float twS[4][16];

    int n = blockIdx.x * 4 + wave;
    if (n >= N) n = N - 1;      // duplicate pair: identical writes, deterministic

    const int b = b_ind[n], h = h_ind[n], t = t_ind[n];
    const int eh = b * Ent + h, et = b * Ent + t;
    const int rh = eh * Mm, rt = et * Mm;
    const int hn = mention_num[eh], tn = mention_num[et];

    const int i  = lane >> 2;       // score row 0..15
    const int jg = lane & 3;        // col group: cols jg*4 .. jg*4+3

    const float chi = ch[rh + i];
    const float cqi = cqt[rt + i];
    const float4 q4 = *reinterpret_cast<const float4*>(qt + rt + jg * 4);
    const u16x4 f4  = *reinterpret_cast<const u16x4*>(
                          f_head + (size_t)(rh + i) * Hd + jg * 4);
    float v[4];
    #pragma unroll
    for (int k = 0; k < 4; ++k) {
        const int j = jg * 4 + k;
        const float qv = (k == 0) ? q4.x : (k == 1) ? q4.y : (k == 2) ? q4.z : q4.w;
        v[k] = (i < hn && j < tn) ? (chi + qv + cqi * bf2f(f4[k])) : NEGV;
    }

    float rm = fmaxf(fmaxf(v[0], v[1]), fmaxf(v[2], v[3]));
    rm = fmaxf(rm, __shfl_xor(rm, 1));
    rm = fmaxf(rm, __shfl_xor(rm, 2));

    float cm[4];
    #pragma unroll
    for (int k = 0; k < 4; ++k) {
        cm[k] = v[k];
        cm[k] = fmaxf(cm[k], __shfl_xor(cm[k], 4));
        cm[k] = fmaxf(cm[k], __shfl_xor(cm[k], 8));
        cm[k] = fmaxf(cm[k], __shfl_xor(cm[k], 16));
        cm[k] = fmaxf(cm[k], __shfl_xor(cm[k], 32));
    }

    float gm = rm;
    gm = fmaxf(gm, __shfl_xor(gm, 4));
    gm = fmaxf(gm, __shfl_xor(gm, 8));
    gm = fmaxf(gm, __shfl_xor(gm, 16));
    gm = fmaxf(gm, __shfl_xor(gm, 32));
    const float eh_ = expf(rm - gm);
    float S = eh_;
    S += __shfl_xor(S, 4);
    S += __shfl_xor(S, 8);
    S += __shfl_xor(S, 16);
    S += __shfl_xor(S, 32);
    const float hwv = eh_ / S;

    float gmt = fmaxf(fmaxf(cm[0], cm[1]), fmaxf(cm[2], cm[3]));
    gmt = fmaxf(gmt, __shfl_xor(gmt, 1));
    gmt = fmaxf(gmt, __shfl_xor(gmt, 2));
    float et_[4];
    float St = 0.f;
    #pragma unroll
    for (int k = 0; k < 4; ++k) { et_[k] = expf(cm[k] - gmt); St += et_[k]; }
    St += __shfl_xor(St, 1);
    St += __shfl_xor(St, 2);

    if (jg == 0) hwS[wave][i] = hwv;
    if (lane < 4) {
        #pragma unroll
        for (int k = 0; k < 4; ++k) twS[wave][lane * 4 + k] = et_[k] / St;
    }
    __syncthreads();

    const size_t oh = (size_t)n * (2 * Hd);
    const size_t ot = (size_t)(N + n) * (2 * Hd);
    const unsigned short* fhp = f_head + (size_t)rh * Hd;
    const unsigned short* ftp = f_tail + (size_t)rt * Hd;

    #pragma unroll
    for (int c = 0; c < 3; ++c) {
        const int col = c * 256 + lane * 4;
        float a0 = 0.f, a1 = 0.f, a2 = 0.f, a3 = 0.f;
        for (int ii = 0; ii < hn; ++ii) {
            const u16x4 fv = *reinterpret_cast<const u16x4*>(fhp + (size_t)ii * Hd + col);
            const float w = hwS[wave][ii];
            a0 += w * bf2f(fv[0]); a1 += w * bf2f(fv[1]);
            a2 += w * bf2f(fv[2]); a3 += w * bf2f(fv[3]);
        }
        float4 o = {a0, a1, a2, a3};
        *reinterpret_cast<float4*>(out + oh + Hd + col) = o;
    }
    #pragma unroll
    for (int c = 0; c < 3; ++c) {
        const int col = c * 256 + lane * 4;
        float a0 = 0.f, a1 = 0.f, a2 = 0.f, a3 = 0.f;
        for (int ii = 0; ii < tn; ++ii) {
            const u16x4 fv = *reinterpret_cast<const u16x4*>(ftp + (size_t)ii * Hd + col);
            const float w = twS[wave][ii];
            a0 += w * bf2f(fv[0]); a1 += w * bf2f(fv[1]);
            a2 += w * bf2f(fv[2]); a3 += w * bf2f(fv[3]);
        }
        float4 o = {a0, a1, a2, a3};
        *reinterpret_cast<float4*>(out + ot + Hd + col) = o;
    }

    const float4* ehp = reinterpret_cast<const float4*>(entity_embed + (size_t)eh * Hd);
    const float4* etp = reinterpret_cast<const float4*>(entity_embed + (size_t)et * Hd);
    #pragma unroll
    for (int c = 0; c < 3; ++c) {
        const int g = c * 64 + lane;
        reinterpret_cast<float4*>(out + oh)[g] = ehp[g];
        reinterpret_cast<float4*>(out + ot)[g] = etp[g];
    }
}

// ---------------------------------------------------------------------------
extern "C" void kernel_launch(void* const* d_in, const int* in_sizes, int n_in,
                              void* d_out, int out_size, void* d_ws, size_t ws_size,
                              hipStream_t stream)
{
    const float* entity_embed  = (const float*)d_in[0];
    const float* mention_embed = (const float*)d_in[1];
    // d_in[2] sent_embed, d_in[3] entity_info: unused by reference
    const int*   mention_num   = (const int*)d_in[4];
    const int*   b_ind         = (const int*)d_in[5];
    const int*   h_ind         = (const int*)d_in[6];
    const int*   t_ind         = (const int*)d_in[7];
    const float* W_head        = (const float*)d_in[8];
    const float* W_tail        = (const float*)d_in[9];
    const float* w_c           = (const float*)d_in[10];
    const float* w_q           = (const float*)d_in[11];
    const float* w_cq          = (const float*)d_in[12];
    float* out = (float*)d_out;

    const int N = in_sizes[5];            // 4096

    // workspace layout (bf16 activations): total ~14.8 MiB
    unsigned short* Ab     = (unsigned short*)d_ws;          // [2688*768]
    unsigned short* Wb     = Ab + (size_t)GM * GK;           // [1536*768] (head||tail)
    unsigned short* f_head = Wb + (size_t)GN * GK;           // [2688*768]
    unsigned short* f_tail = f_head + (size_t)GM * Hd;       // [2688*768]
    float* ch  = (float*)(f_tail + (size_t)GM * Hd);         // [2688]
    float* qt  = ch + GM;                                    // [2688]
    float* cqt = qt + GM;                                    // [2688]

    // 0) convert inputs to bf16
    to_bf16<<<(GM + GN) * GK / (8 * 256), 256, 0, stream>>>(
        mention_embed, W_head, W_tail, Ab);

    // 1) GEMM + ReLU (BK=64, swizzled LDS)
    dim3 gg(GN / 128, GM / 64);           // (12, 42) = 504 blocks
    gemm_mfma<<<gg, 256, 0, stream>>>(Ab, Wb, f_head, f_tail);

    // 2) per-row dots
    row_dots<<<GM / 4, 256, 0, stream>>>(f_head, f_tail, w_c, w_q, w_cq, ch, qt, cqt);

    // 3) per-pair attention + output (wave per pair)
    pair_attn<<<(N + 3) / 4, 256, 0, stream>>>(f_head, f_tail, ch, qt, cqt,
                                               entity_embed, mention_num,
                                               b_ind, h_ind, t_ind, out, N);
}

// Round 11
// 44.382 us; speedup vs baseline: 1.5966x; 1.0600x over previous
//
#include <hip/hip_runtime.h>
#include <hip/hip_bf16.h>

// Problem constants (from reference)
#define Hd   768
#define Bsz  4
#define Ent  42
#define Mm   16
#define NEGV (-1e9f)

#define GM 2688          // B*E*M rows
#define GN 1536          // concat(head, tail) outputs
#define GK 768
#define NT2 (GK / 64)    // 12 K-steps of 64

typedef short bf16x8 __attribute__((ext_vector_type(8)));
typedef float f32x4  __attribute__((ext_vector_type(4)));
typedef unsigned short u16x8 __attribute__((ext_vector_type(8)));
typedef unsigned short u16x4 __attribute__((ext_vector_type(4)));

static __device__ __forceinline__ unsigned short f2bf(float x) {
    unsigned int u = __float_as_uint(x);
    u += 0x7fffu + ((u >> 16) & 1u);          // RNE
    return (unsigned short)(u >> 16);
}
static __device__ __forceinline__ float bf2f(unsigned short v) {
    return __uint_as_float(((unsigned int)v) << 16);
}

// ---------------------------------------------------------------------------
// Kernel 0: fp32 -> bf16 conversion (round-7 proven).
// ---------------------------------------------------------------------------
__global__ __launch_bounds__(256)
void to_bf16(const float* __restrict__ me, const float* __restrict__ wh,
             const float* __restrict__ wt, unsigned short* __restrict__ dst)
{
    const int t = blockIdx.x * 256 + threadIdx.x;
    const size_t e = (size_t)t * 8;
    const size_t row = e / Hd;                         // 8 | 768 so no straddle
    const float* src;
    size_t off;
    if (row < 2688)      { src = me; off = e; }
    else if (row < 3456) { src = wh; off = e - (size_t)2688 * Hd; }
    else                 { src = wt; off = e - (size_t)3456 * Hd; }
    float4 v0 = *reinterpret_cast<const float4*>(src + off);
    float4 v1 = *reinterpret_cast<const float4*>(src + off + 4);
    u16x8 o;
    o[0] = f2bf(v0.x); o[1] = f2bf(v0.y); o[2] = f2bf(v0.z); o[3] = f2bf(v0.w);
    o[4] = f2bf(v1.x); o[5] = f2bf(v1.y); o[6] = f2bf(v1.z); o[7] = f2bf(v1.w);
    *reinterpret_cast<u16x8*>(dst + e) = o;
}

// ---------------------------------------------------------------------------
// Kernel 1: bf16 MFMA GEMM + ReLU, BK=64 + T2 both-sides swizzle
// (round-10 proven, byte-identical).
// ---------------------------------------------------------------------------
__global__ __launch_bounds__(256)
void gemm_mfma(const unsigned short* __restrict__ Ab,
               const unsigned short* __restrict__ Wb,
               unsigned short* __restrict__ f_head,
               unsigned short* __restrict__ f_tail)
{
    __shared__ unsigned short As[2][64 * 64];    //  8 KB per buf
    __shared__ unsigned short Bs[2][128 * 64];   // 16 KB per buf

    const int tid  = threadIdx.x;
    const int wave = tid >> 6;
    const int lane = tid & 63;
    const int n0 = blockIdx.x * 128;
    const int m0 = blockIdx.y * 64;

    const int sr8   = lane >> 3;                       // 0..7 row in stripe
    const int scolE = ((lane & 7) ^ sr8) * 8;          // swizzled src col (elems)
    const unsigned short* AgaBase = Ab + (size_t)(m0 + wave * 16 + sr8) * GK + scolE;
    const unsigned short* BgaBase = Wb + (size_t)(n0 + wave * 32 + sr8) * GK + scolE;

#define STAGE(buf, k0) do { \
    __builtin_amdgcn_global_load_lds((const __attribute__((address_space(1))) void*)(AgaBase + (k0)), \
        (__attribute__((address_space(3))) void*)(As[buf] + (wave * 16) * 64), 16, 0, 0); \
    __builtin_amdgcn_global_load_lds((const __attribute__((address_space(1))) void*)(AgaBase + 8 * GK + (k0)), \
        (__attribute__((address_space(3))) void*)(As[buf] + (wave * 16 + 8) * 64), 16, 0, 0); \
    __builtin_amdgcn_global_load_lds((const __attribute__((address_space(1))) void*)(BgaBase + (k0)), \
        (__attribute__((address_space(3))) void*)(Bs[buf] + (wave * 32) * 64), 16, 0, 0); \
    __builtin_amdgcn_global_load_lds((const __attribute__((address_space(1))) void*)(BgaBase + 8 * GK + (k0)), \
        (__attribute__((address_space(3))) void*)(Bs[buf] + (wave * 32 + 8) * 64), 16, 0, 0); \
    __builtin_amdgcn_global_load_lds((const __attribute__((address_space(1))) void*)(BgaBase + 16 * GK + (k0)), \
        (__attribute__((address_space(3))) void*)(Bs[buf] + (wave * 32 + 16) * 64), 16, 0, 0); \
    __builtin_amdgcn_global_load_lds((const __attribute__((address_space(1))) void*)(BgaBase + 24 * GK + (k0)), \
        (__attribute__((address_space(3))) void*)(Bs[buf] + (wave * 32 + 24) * 64), 16, 0, 0); \
} while (0)

    const int frow = lane & 15;
    const int kg   = lane >> 4;
    const int f7x  = (frow & 7) << 4;                  // byte XOR key (row-det.)
    const int rdE0 = ((kg * 16)      ^ f7x) >> 1;      // elems, k-half 0
    const int rdE1 = ((kg * 16 + 64) ^ f7x) >> 1;      // elems, k-half 1

    f32x4 acc[4][2];
    {
        f32x4 z = {0.f, 0.f, 0.f, 0.f};
        #pragma unroll
        for (int mi = 0; mi < 4; ++mi) { acc[mi][0] = z; acc[mi][1] = z; }
    }

    STAGE(0, 0);
    int cur = 0;
    #pragma unroll 1
    for (int t = 0; t < NT2; ++t) {
        __syncthreads();                 // drains vmcnt: buf[cur] ready
        if (t < NT2 - 1) STAGE(cur ^ 1, (t + 1) * 64);
        const unsigned short* a_ = As[cur] + frow * 64;
        const unsigned short* b_ = Bs[cur] + (wave * 32 + frow) * 64;
        bf16x8 a[4][2], b[2][2];
        #pragma unroll
        for (int mi = 0; mi < 4; ++mi) {
            a[mi][0] = *reinterpret_cast<const bf16x8*>(a_ + mi * 16 * 64 + rdE0);
            a[mi][1] = *reinterpret_cast<const bf16x8*>(a_ + mi * 16 * 64 + rdE1);
        }
        #pragma unroll
        for (int ni = 0; ni < 2; ++ni) {
            b[ni][0] = *reinterpret_cast<const bf16x8*>(b_ + ni * 16 * 64 + rdE0);
            b[ni][1] = *reinterpret_cast<const bf16x8*>(b_ + ni * 16 * 64 + rdE1);
        }
        #pragma unroll
        for (int kk = 0; kk < 2; ++kk)           // ascending k: bit-identical
            #pragma unroll
            for (int mi = 0; mi < 4; ++mi) {
                acc[mi][0] = __builtin_amdgcn_mfma_f32_16x16x32_bf16(a[mi][kk], b[0][kk], acc[mi][0], 0, 0, 0);
                acc[mi][1] = __builtin_amdgcn_mfma_f32_16x16x32_bf16(a[mi][kk], b[1][kk], acc[mi][1], 0, 0, 0);
            }
        cur ^= 1;
    }
#undef STAGE

    // C/D layout (m89-verified): col = frow, row = kg*4 + reg.
    const bool isHead = (n0 < Hd);
    unsigned short* outp = isHead ? f_head : f_tail;
    const int nbase = (isHead ? n0 : (n0 - Hd)) + wave * 32 + frow;
    const int rbase = m0 + kg * 4;
    #pragma unroll
    for (int mi = 0; mi < 4; ++mi)
        #pragma unroll
        for (int ni = 0; ni < 2; ++ni)
            #pragma unroll
            for (int j = 0; j < 4; ++j) {
                float v = fmaxf(acc[mi][ni][j], 0.f);
                outp[(size_t)(rbase + mi * 16 + j) * Hd + nbase + ni * 16] = f2bf(v);
            }
}

// ---------------------------------------------------------------------------
// Kernel 2: per-row dots (round-7 proven).
// ---------------------------------------------------------------------------
__global__ __launch_bounds__(256)
void row_dots(const unsigned short* __restrict__ f_head,
              const unsigned short* __restrict__ f_tail,
              const float* __restrict__ w_c, const float* __restrict__ w_q,
              const float* __restrict__ w_cq,
              float* __restrict__ ch, float* __restrict__ qt, float* __restrict__ cqt)
{
    const int wave = threadIdx.x >> 6;
    const int lane = threadIdx.x & 63;
    const int r = blockIdx.x * 4 + wave;
    const unsigned short* fh = f_head + (size_t)r * Hd;
    const unsigned short* ft = f_tail + (size_t)r * Hd;
    float pc = 0.f, pq = 0.f, pcq = 0.f;
    #pragma unroll
    for (int j = 0; j < Hd / 64; ++j) {
        const int c = j * 64 + lane;
        float vh = bf2f(fh[c]), vt = bf2f(ft[c]);
        pc += vh * w_c[c]; pq += vt * w_q[c]; pcq += vt * w_cq[c];
    }
    #pragma unroll
    for (int s = 32; s >= 1; s >>= 1) {
        pc  += __shfl_down(pc, s);
        pq  += __shfl_down(pq, s);
        pcq += __shfl_down(pcq, s);
    }
    if (lane == 0) { ch[r] = pc; qt[r] = pq; cqt[r] = pcq; }
}

// ---------------------------------------------------------------------------
// Kernel 3: ONE WAVE PER PAIR attention.  vs round 10: the pooling is
// restructured for memory-level parallelism -- one pass over rows per half,
// 3 independent chunk-loads per row, 2 rows per step (6 loads in flight vs
// ~1 before).  Per-accumulator fma order remains ascending-ii: bit-identical.
// ---------------------------------------------------------------------------
__global__ __launch_bounds__(256)
void pair_attn(const unsigned short* __restrict__ f_head,
               const unsigned short* __restrict__ f_tail,
               const float* __restrict__ ch, const float* __restrict__ qt,
               const float* __restrict__ cqt,
               const float* __restrict__ entity_embed,
               const int* __restrict__ mention_num,
               const int* __restrict__ b_ind, const int* __restrict__ h_ind,
               const int* __restrict__ t_ind,
               float* __restrict__ out, int N)
{
    const int tid  = threadIdx.x;
    const int wave = tid >> 6;
    const int lane = tid & 63;

    __shared__ float hwS[4][16];
    __shared__ float twS[4][16];

    int n = blockIdx.x * 4 + wave;
    if (n >= N) n = N - 1;      // duplicate pair: identical writes, deterministic

    const int b = b_ind[n], h = h_ind[n], t = t_ind[n];
    const int eh = b * Ent + h, et = b * Ent + t;
    const int rh = eh * Mm, rt = et * Mm;
    const int hn = mention_num[eh], tn = mention_num[et];

    const int i  = lane >> 2;       // score row 0..15
    const int jg = lane & 3;        // col group: cols jg*4 .. jg*4+3

    const float chi = ch[rh + i];
    const float cqi = cqt[rt + i];
    const float4 q4 = *reinterpret_cast<const float4*>(qt + rt + jg * 4);
    const u16x4 f4  = *reinterpret_cast<const u16x4*>(
                          f_head + (size_t)(rh + i) * Hd + jg * 4);
    float v[4];
    #pragma unroll
    for (int k = 0; k < 4; ++k) {
        const int j = jg * 4 + k;
        const float qv = (k == 0) ? q4.x : (k == 1) ? q4.y : (k == 2) ? q4.z : q4.w;
        v[k] = (i < hn && j < tn) ? (chi + qv + cqi * bf2f(f4[k])) : NEGV;
    }

    float rm = fmaxf(fmaxf(v[0], v[1]), fmaxf(v[2], v[3]));
    rm = fmaxf(rm, __shfl_xor(rm, 1));
    rm = fmaxf(rm, __shfl_xor(rm, 2));

    float cm[4];
    #pragma unroll
    for (int k = 0; k < 4; ++k) {
        cm[k] = v[k];
        cm[k] = fmaxf(cm[k], __shfl_xor(cm[k], 4));
        cm[k] = fmaxf(cm[k], __shfl_xor(cm[k], 8));
        cm[k] = fmaxf(cm[k], __shfl_xor(cm[k], 16));
        cm[k] = fmaxf(cm[k], __shfl_xor(cm[k], 32));
    }

    float gm = rm;
    gm = fmaxf(gm, __shfl_xor(gm, 4));
    gm = fmaxf(gm, __shfl_xor(gm, 8));
    gm = fmaxf(gm, __shfl_xor(gm, 16));
    gm = fmaxf(gm, __shfl_xor(gm, 32));
    const float eh_ = expf(rm - gm);
    float S = eh_;
    S += __shfl_xor(S, 4);
    S += __shfl_xor(S, 8);
    S += __shfl_xor(S, 16);
    S += __shfl_xor(S, 32);
    const float hwv = eh_ / S;

    float gmt = fmaxf(fmaxf(cm[0], cm[1]), fmaxf(cm[2], cm[3]));
    gmt = fmaxf(gmt, __shfl_xor(gmt, 1));
    gmt = fmaxf(gmt, __shfl_xor(gmt, 2));
    float et_[4];
    float St = 0.f;
    #pragma unroll
    for (int k = 0; k < 4; ++k) { et_[k] = expf(cm[k] - gmt); St += et_[k]; }
    St += __shfl_xor(St, 1);
    St += __shfl_xor(St, 2);

    if (jg == 0) hwS[wave][i] = hwv;
    if (lane < 4) {
        #pragma unroll
        for (int k = 0; k < 4; ++k) twS[wave][lane * 4 + k] = et_[k] / St;
    }
    __syncthreads();

    const size_t oh = (size_t)n * (2 * Hd);
    const size_t ot = (size_t)(N + n) * (2 * Hd);
    const unsigned short* fhp = f_head + (size_t)rh * Hd;
    const unsigned short* ftp = f_tail + (size_t)rt * Hd;

    // ---- head pooling: single pass over rows, 3 chunks/row, 2 rows/step ---
    {
        float a[12];
        #pragma unroll
        for (int j = 0; j < 12; ++j) a[j] = 0.f;
        int ii = 0;
        for (; ii + 2 <= hn; ii += 2) {
            u16x4 r0[3], r1[3];
            #pragma unroll
            for (int c = 0; c < 3; ++c) {
                r0[c] = *reinterpret_cast<const u16x4*>(fhp + (size_t)ii * Hd + c * 256 + lane * 4);
                r1[c] = *reinterpret_cast<const u16x4*>(fhp + (size_t)(ii + 1) * Hd + c * 256 + lane * 4);
            }
            const float w0 = hwS[wave][ii], w1 = hwS[wave][ii + 1];
            #pragma unroll
            for (int c = 0; c < 3; ++c)
                #pragma unroll
                for (int k = 0; k < 4; ++k) {
                    a[c * 4 + k] += w0 * bf2f(r0[c][k]);   // ascending ii:
                    a[c * 4 + k] += w1 * bf2f(r1[c][k]);   // bit-identical order
                }
        }
        if (ii < hn) {
            u16x4 r0[3];
            #pragma unroll
            for (int c = 0; c < 3; ++c)
                r0[c] = *reinterpret_cast<const u16x4*>(fhp + (size_t)ii * Hd + c * 256 + lane * 4);
            const float w0 = hwS[wave][ii];
            #pragma unroll
            for (int c = 0; c < 3; ++c)
                #pragma unroll
                for (int k = 0; k < 4; ++k)
                    a[c * 4 + k] += w0 * bf2f(r0[c][k]);
        }
        #pragma unroll
        for (int c = 0; c < 3; ++c) {
            float4 o = {a[c * 4], a[c * 4 + 1], a[c * 4 + 2], a[c * 4 + 3]};
            *reinterpret_cast<float4*>(out + oh + Hd + c * 256 + lane * 4) = o;
        }
    }

    // ---- tail pooling: same structure ----
    {
        float a[12];
        #pragma unroll
        for (int j = 0; j < 12; ++j) a[j] = 0.f;
        int ii = 0;
        for (; ii + 2 <= tn; ii += 2) {
            u16x4 r0[3], r1[3];
            #pragma unroll
            for (int c = 0; c < 3; ++c) {
                r0[c] = *reinterpret_cast<const u16x4*>(ftp + (size_t)ii * Hd + c * 256 + lane * 4);
                r1[c] = *reinterpret_cast<const u16x4*>(ftp + (size_t)(ii + 1) * Hd + c * 256 + lane * 4);
            }
            const float w0 = twS[wave][ii], w1 = twS[wave][ii + 1];
            #pragma unroll
            for (int c = 0; c < 3; ++c)
                #pragma unroll
                for (int k = 0; k < 4; ++k) {
                    a[c * 4 + k] += w0 * bf2f(r0[c][k]);
                    a[c * 4 + k] += w1 * bf2f(r1[c][k]);
                }
        }
        if (ii < tn) {
            u16x4 r0[3];
            #pragma unroll
            for (int c = 0; c < 3; ++c)
                r0[c] = *reinterpret_cast<const u16x4*>(ftp + (size_t)ii * Hd + c * 256 + lane * 4);
            const float w0 = twS[wave][ii];
            #pragma unroll
            for (int c = 0; c < 3; ++c)
                #pragma unroll
                for (int k = 0; k < 4; ++k)
                    a[c * 4 + k] += w0 * bf2f(r0[c][k]);
        }
        #pragma unroll
        for (int c = 0; c < 3; ++c) {
            float4 o = {a[c * 4], a[c * 4 + 1], a[c * 4 + 2], a[c * 4 + 3]};
            *reinterpret_cast<float4*>(out + ot + Hd + c * 256 + lane * 4) = o;
        }
    }

    // ---- entity embed copy: 2 x 192 float4, lane covers 3 each ----
    const float4* ehp = reinterpret_cast<const float4*>(entity_embed + (size_t)eh * Hd);
    const float4* etp = reinterpret_cast<const float4*>(entity_embed + (size_t)et * Hd);
    #pragma unroll
    for (int c = 0; c < 3; ++c) {
        const int g = c * 64 + lane;
        reinterpret_cast<float4*>(out + oh)[g] = ehp[g];
        reinterpret_cast<float4*>(out + ot)[g] = etp[g];
    }
}

// ---------------------------------------------------------------------------
extern "C" void kernel_launch(void* const* d_in, const int* in_sizes, int n_in,
                              void* d_out, int out_size, void* d_ws, size_t ws_size,
                              hipStream_t stream)
{
    const float* entity_embed  = (const float*)d_in[0];
    const float* mention_embed = (const float*)d_in[1];
    // d_in[2] sent_embed, d_in[3] entity_info: unused by reference
    const int*   mention_num   = (const int*)d_in[4];
    const int*   b_ind         = (const int*)d_in[5];
    const int*   h_ind         = (const int*)d_in[6];
    const int*   t_ind         = (const int*)d_in[7];
    const float* W_head        = (const float*)d_in[8];
    const float* W_tail        = (const float*)d_in[9];
    const float* w_c           = (const float*)d_in[10];
    const float* w_q           = (const float*)d_in[11];
    const float* w_cq          = (const float*)d_in[12];
    float* out = (float*)d_out;

    const int N = in_sizes[5];            // 4096

    // workspace layout (bf16 activations): total ~14.8 MiB
    unsigned short* Ab     = (unsigned short*)d_ws;          // [2688*768]
    unsigned short* Wb     = Ab + (size_t)GM * GK;           // [1536*768] (head||tail)
    unsigned short* f_head = Wb + (size_t)GN * GK;           // [2688*768]
    unsigned short* f_tail = f_head + (size_t)GM * Hd;       // [2688*768]
    float* ch  = (float*)(f_tail + (size_t)GM * Hd);         // [2688]
    float* qt  = ch + GM;                                    // [2688]
    float* cqt = qt + GM;                                    // [2688]

    // 0) convert inputs to bf16
    to_bf16<<<(GM + GN) * GK / (8 * 256), 256, 0, stream>>>(
        mention_embed, W_head, W_tail, Ab);

    // 1) GEMM + ReLU (BK=64, swizzled LDS)
    dim3 gg(GN / 128, GM / 64);           // (12, 42) = 504 blocks
    gemm_mfma<<<gg, 256, 0, stream>>>(Ab, Wb, f_head, f_tail);

    // 2) per-row dots
    row_dots<<<GM / 4, 256, 0, stream>>>(f_head, f_tail, w_c, w_q, w_cq, ch, qt, cqt);

    // 3) per-pair attention + output (wave per pair, MLP pooling)
    pair_attn<<<(N + 3) / 4, 256, 0, stream>>>(f_head, f_tail, ch, qt, cqt,
                                               entity_embed, mention_num,
                                               b_ind, h_ind, t_ind, out, N);
}